// Round 2
// baseline (3174.576 us; speedup 1.0000x reference)
//
#include <hip/hip_runtime.h>
#include <math.h>

#define N_NODES 4096
#define N_IN    512
#define N_H     512
#define S_SEL   10

#define BM 64
#define BN 64
#define BK 16

// ---------------------------------------------------------------------------
// C[M,N] = A[M,K] @ B[K,N] + bias[n], then PReLU(slope)
__global__ __launch_bounds__(256) void gemm_nn_bias_prelu(
    const float* __restrict__ A, const float* __restrict__ B,
    const float* __restrict__ bias, const float* __restrict__ slope,
    float* __restrict__ C, int M, int N, int K)
{
    __shared__ float As[BK][BM + 1];
    __shared__ float Bs[BK][BN + 1];
    const int tid = threadIdx.x;
    const int tx = tid & 15, ty = tid >> 4;
    const int bm = blockIdx.y * BM, bn = blockIdx.x * BN;
    float acc[4][4] = {};
    for (int k0 = 0; k0 < K; k0 += BK) {
#pragma unroll
        for (int p = 0; p < 4; ++p) {
            int m = p * 16 + ty;
            As[tx][m] = A[(size_t)(bm + m) * K + k0 + tx];
        }
#pragma unroll
        for (int p = 0; p < 4; ++p) {
            int kk = p * 4 + (tid >> 6);
            int n = tid & 63;
            Bs[kk][n] = B[(size_t)(k0 + kk) * N + bn + n];
        }
        __syncthreads();
#pragma unroll
        for (int kk = 0; kk < BK; ++kk) {
            float a[4], b[4];
#pragma unroll
            for (int i = 0; i < 4; ++i) a[i] = As[kk][ty + 16 * i];
#pragma unroll
            for (int j = 0; j < 4; ++j) b[j] = Bs[kk][tx + 16 * j];
#pragma unroll
            for (int i = 0; i < 4; ++i)
#pragma unroll
                for (int j = 0; j < 4; ++j)
                    acc[i][j] = fmaf(a[i], b[j], acc[i][j]);
        }
        __syncthreads();
    }
    const float s = slope[0];
#pragma unroll
    for (int i = 0; i < 4; ++i) {
        int gm = bm + ty + 16 * i;
#pragma unroll
        for (int j = 0; j < 4; ++j) {
            int gn = bn + tx + 16 * j;
            float v = acc[i][j] + bias[gn];
            v = v >= 0.f ? v : s * v;
            C[(size_t)gm * N + gn] = v;
        }
    }
}

// ---------------------------------------------------------------------------
// EPI 0: C[M,N] = A[M,K] @ B[N,K]^T           (raw store)
// EPI 1: v = acc * rinv[gm] * rinv[gn]; C = expf(2*v*v)   (node similarity)
template <int EPI>
__global__ __launch_bounds__(256) void gemm_nt(
    const float* __restrict__ A, const float* __restrict__ B,
    const float* __restrict__ rinv,
    float* __restrict__ C, int M, int N, int K)
{
    __shared__ float As[BK][BM + 1];
    __shared__ float Bs[BK][BN + 1];
    const int tid = threadIdx.x;
    const int tx = tid & 15, ty = tid >> 4;
    const int bm = blockIdx.y * BM, bn = blockIdx.x * BN;
    float acc[4][4] = {};
    for (int k0 = 0; k0 < K; k0 += BK) {
#pragma unroll
        for (int p = 0; p < 4; ++p) {
            int m = p * 16 + ty;
            As[tx][m] = A[(size_t)(bm + m) * K + k0 + tx];
            Bs[tx][m] = B[(size_t)(bn + m) * K + k0 + tx];
        }
        __syncthreads();
#pragma unroll
        for (int kk = 0; kk < BK; ++kk) {
            float a[4], b[4];
#pragma unroll
            for (int i = 0; i < 4; ++i) a[i] = As[kk][ty + 16 * i];
#pragma unroll
            for (int j = 0; j < 4; ++j) b[j] = Bs[kk][tx + 16 * j];
#pragma unroll
            for (int i = 0; i < 4; ++i)
#pragma unroll
                for (int j = 0; j < 4; ++j)
                    acc[i][j] = fmaf(a[i], b[j], acc[i][j]);
        }
        __syncthreads();
    }
#pragma unroll
    for (int i = 0; i < 4; ++i) {
        int gm = bm + ty + 16 * i;
#pragma unroll
        for (int j = 0; j < 4; ++j) {
            int gn = bn + tx + 16 * j;
            if (EPI == 0) {
                C[(size_t)gm * N + gn] = acc[i][j];
            } else {
                float v = acc[i][j] * rinv[gm] * rinv[gn];
                C[(size_t)gm * N + gn] = expf(2.f * v * v);
            }
        }
    }
}

// ---------------------------------------------------------------------------
// simf[i,j] = expf(2 * ((Z^T Z)[i,j] * cninv[i] * cninv[j])^2), 512x512, K=4096
__global__ __launch_bounds__(256) void gemm_tn_simf(
    const float* __restrict__ Zm, const float* __restrict__ cninv,
    float* __restrict__ simf)
{
    __shared__ float As[BK][BM + 1];
    __shared__ float Bs[BK][BN + 1];
    const int tid = threadIdx.x;
    const int tx = tid & 15, ty = tid >> 4;
    const int bm = blockIdx.y * BM, bn = blockIdx.x * BN;
    float acc[4][4] = {};
    for (int k0 = 0; k0 < N_NODES; k0 += BK) {
#pragma unroll
        for (int p = 0; p < 4; ++p) {
            int kk = p * 4 + (tid >> 6);
            int m = tid & 63;
            As[kk][m] = Zm[(size_t)(k0 + kk) * N_H + bm + m];
            Bs[kk][m] = Zm[(size_t)(k0 + kk) * N_H + bn + m];
        }
        __syncthreads();
#pragma unroll
        for (int kk = 0; kk < BK; ++kk) {
            float a[4], b[4];
#pragma unroll
            for (int i = 0; i < 4; ++i) a[i] = As[kk][ty + 16 * i];
#pragma unroll
            for (int j = 0; j < 4; ++j) b[j] = Bs[kk][tx + 16 * j];
#pragma unroll
            for (int i = 0; i < 4; ++i)
#pragma unroll
                for (int j = 0; j < 4; ++j)
                    acc[i][j] = fmaf(a[i], b[j], acc[i][j]);
        }
        __syncthreads();
    }
#pragma unroll
    for (int i = 0; i < 4; ++i) {
        int gm = bm + ty + 16 * i;
#pragma unroll
        for (int j = 0; j < 4; ++j) {
            int gn = bn + tx + 16 * j;
            float v = acc[i][j] * cninv[gm] * cninv[gn];
            simf[(size_t)gm * N_H + gn] = expf(2.f * v * v);
        }
    }
}

// ---------------------------------------------------------------------------
__global__ void init_out(float* out)
{
    if (threadIdx.x == 0) { out[16384] = 0.f; out[16385] = 0.f; }
}

// column mean over 4096 rows -> sigmoid. grid 8 blocks x 256 thr.
__global__ __launch_bounds__(256) void colmean_sigmoid(
    const float* __restrict__ Hm, float* __restrict__ c)
{
    __shared__ float part[4][64];
    const int tcol = threadIdx.x & 63;
    const int trow = threadIdx.x >> 6;
    const int col = blockIdx.x * 64 + tcol;
    float s = 0.f;
#pragma unroll 4
    for (int r = trow * 1024; r < (trow + 1) * 1024; ++r)
        s += Hm[(size_t)r * N_H + col];
    part[trow][tcol] = s;
    __syncthreads();
    if (trow == 0) {
        float t = part[0][tcol] + part[1][tcol] + part[2][tcol] + part[3][tcol];
        t *= (1.f / N_NODES);
        c[col] = 1.f / (1.f + expf(-t));
    }
}

// column sum of squares of Z. grid 8 x 256.
__global__ __launch_bounds__(256) void colsumsq_kernel(
    const float* __restrict__ Zm, float* __restrict__ cn2)
{
    __shared__ float part[4][64];
    const int tcol = threadIdx.x & 63;
    const int trow = threadIdx.x >> 6;
    const int col = blockIdx.x * 64 + tcol;
    float s = 0.f;
#pragma unroll 4
    for (int r = trow * 1024; r < (trow + 1) * 1024; ++r) {
        float z = Zm[(size_t)r * N_H + col];
        s = fmaf(z, z, s);
    }
    part[trow][tcol] = s;
    __syncthreads();
    if (trow == 0)
        cn2[col] = part[0][tcol] + part[1][tcol] + part[2][tcol] + part[3][tcol];
}

// Z = h1 + h2, row sum of squares. one wave per row, grid 1024 x 256.
__global__ __launch_bounds__(256) void z_rowsumsq(
    const float* __restrict__ h1, const float* __restrict__ h2,
    float* __restrict__ Zm, float* __restrict__ rs)
{
    const int w = (int)((blockIdx.x * blockDim.x + threadIdx.x) >> 6);
    const int lane = threadIdx.x & 63;
    if (w >= N_NODES) return;
    float ss = 0.f;
#pragma unroll
    for (int t = 0; t < N_H; t += 64) {
        size_t idx = (size_t)w * N_H + t + lane;
        float z = h1[idx] + h2[idx];
        Zm[idx] = z;
        ss = fmaf(z, z, ss);
    }
#pragma unroll
    for (int off = 32; off > 0; off >>= 1) ss += __shfl_down(ss, off, 64);
    if (lane == 0) rs[w] = ss;
}

__global__ void invnorm(const float* __restrict__ ss, float* __restrict__ inv, int n)
{
    int i = blockIdx.x * blockDim.x + threadIdx.x;
    if (i < n) inv[i] = 1.f / fmaxf(sqrtf(ss[i]), 1e-12f);
}

// v1 = Wd @ c1, v2 = Wd @ c2. one wave per output row; grid 256 x 256.
__global__ __launch_bounds__(256) void bilinear_vec(
    const float* __restrict__ Wd, const float* __restrict__ c1,
    const float* __restrict__ c2, float* __restrict__ v1, float* __restrict__ v2)
{
    const int w = (int)((blockIdx.x * blockDim.x + threadIdx.x) >> 6);
    const int lane = threadIdx.x & 63;
    if (w >= 2 * N_H) return;
    const float* c = (w < N_H) ? c1 : c2;
    float* v = (w < N_H) ? v1 : v2;
    const int r = (w < N_H) ? w : w - N_H;
    float s = 0.f;
#pragma unroll
    for (int t = 0; t < N_H; t += 64)
        s = fmaf(Wd[(size_t)r * N_H + t + lane], c[t + lane], s);
#pragma unroll
    for (int off = 32; off > 0; off >>= 1) s += __shfl_down(s, off, 64);
    if (lane == 0) v[r] = s;
}

// ret: [disc(h2,c1), disc(h1,c2), disc(h4,c1), disc(h3,c2)]. one wave/row.
__global__ __launch_bounds__(256) void disc_kernel(
    const float* __restrict__ h1, const float* __restrict__ h2,
    const float* __restrict__ h3, const float* __restrict__ h4,
    const float* __restrict__ v1, const float* __restrict__ v2,
    const float* __restrict__ bd, float* __restrict__ out)
{
    const int w = (int)((blockIdx.x * blockDim.x + threadIdx.x) >> 6);
    const int lane = threadIdx.x & 63;
    if (w >= 4 * N_NODES) return;
    const int seg = w >> 12, r = w & 4095;
    const float* hs = (seg == 0) ? h2 : (seg == 1) ? h1 : (seg == 2) ? h4 : h3;
    const float* vs = (seg == 0 || seg == 2) ? v1 : v2;
    float s = 0.f;
#pragma unroll
    for (int t = 0; t < N_H; t += 64)
        s = fmaf(hs[(size_t)r * N_H + t + lane], vs[t + lane], s);
#pragma unroll
    for (int off = 32; off > 0; off >>= 1) s += __shfl_down(s, off, 64);
    if (lane == 0) out[(size_t)seg * N_NODES + r] = s + bd[0];
}

// pos_n[i] = sum_j sim[i,j] * label[i,j]. block per row.
__global__ __launch_bounds__(256) void posn_kernel(
    const float* __restrict__ sim, const float* __restrict__ label,
    float* __restrict__ posn)
{
    const int row = blockIdx.x;
    const int tid = threadIdx.x;
    float s = 0.f;
    for (int j = tid; j < N_NODES; j += 256) {
        size_t idx = (size_t)row * N_NODES + j;
        s = fmaf(sim[idx], label[idx], s);
    }
    __shared__ float red[4];
#pragma unroll
    for (int off = 32; off > 0; off >>= 1) s += __shfl_down(s, off, 64);
    if ((tid & 63) == 0) red[tid >> 6] = s;
    __syncthreads();
    if (tid == 0) posn[row] = red[0] + red[1] + red[2] + red[3];
}

// ---------------------------------------------------------------------------
template <int L>
__device__ void bitonic_sort(float* buf)
{
    const int tid = threadIdx.x;
    for (int k = 2; k <= L; k <<= 1) {
        for (int j = k >> 1; j > 0; j >>= 1) {
            for (int i = tid; i < L; i += 256) {
                int ixj = i ^ j;
                if (ixj > i) {
                    float a = buf[i], b = buf[ixj];
                    bool up = ((i & k) == 0);
                    if ((a > b) == up) { buf[i] = b; buf[ixj] = a; }
                }
            }
            __syncthreads();
        }
    }
}

// feat loss: per column j (symmetric -> read row j), sort 512, sum 10 ranks.
__global__ __launch_bounds__(256) void feat_sort_kernel(
    const float* __restrict__ simf, const int* __restrict__ fidx,
    float* __restrict__ out)
{
    __shared__ float buf[N_H];
    const int j = blockIdx.x, tid = threadIdx.x;
    for (int i = tid; i < N_H; i += 256) buf[i] = simf[(size_t)j * N_H + i];
    __syncthreads();
    bitonic_sort<N_H>(buf);
    if (tid == 0) {
        float neg = 0.f;
        for (int s = 0; s < S_SEL; ++s) neg += buf[fidx[s]];
        float pos = simf[(size_t)j * N_H + j];
        atomicAdd(out + 16384, (logf(neg) - logf(pos)) * (1.f / N_H));
    }
}

// node loss: per column j (symmetric -> read row j), sort 4096, sum 10 ranks.
__global__ __launch_bounds__(256) void node_sort_kernel(
    const float* __restrict__ sim, const int* __restrict__ nidx,
    const float* __restrict__ posn, float* __restrict__ out)
{
    __shared__ float buf[N_NODES];
    const int j = blockIdx.x, tid = threadIdx.x;
    for (int i = tid; i < N_NODES; i += 256) buf[i] = sim[(size_t)j * N_NODES + i];
    __syncthreads();
    bitonic_sort<N_NODES>(buf);
    if (tid == 0) {
        float neg = 0.f;
        for (int s = 0; s < S_SEL; ++s) neg += buf[nidx[s]];
        atomicAdd(out + 16385, (logf(neg) - logf(posn[j])) * (1.f / N_NODES));
    }
}

// ---------------------------------------------------------------------------
extern "C" void kernel_launch(void* const* d_in, const int* in_sizes, int n_in,
                              void* d_out, int out_size, void* d_ws, size_t ws_size,
                              hipStream_t stream)
{
    const float* seq1  = (const float*)d_in[0];
    const float* seq2  = (const float*)d_in[1];
    const float* adj   = (const float*)d_in[2];
    const float* diff  = (const float*)d_in[3];
    const float* label = (const float*)d_in[4];
    const int*   fidx  = (const int*)d_in[5];
    const int*   nidx  = (const int*)d_in[6];
    const float* W1    = (const float*)d_in[7];
    const float* b1    = (const float*)d_in[8];
    const float* a1    = (const float*)d_in[9];
    const float* W2    = (const float*)d_in[10];
    const float* b2    = (const float*)d_in[11];
    const float* a2    = (const float*)d_in[12];
    const float* Wd    = (const float*)d_in[13];
    const float* bd    = (const float*)d_in[14];
    float* out = (float*)d_out;
    float* ws = (float*)d_ws;

    // workspace layout (floats). sim_n (16M floats) reuses [0,16M) after disc.
    const size_t SZH = (size_t)N_NODES * N_H;        // 2097152
    float* fts1 = ws;
    float* fts2 = fts1 + SZH;
    float* fts3 = fts2 + SZH;
    float* fts4 = fts3 + SZH;
    float* h1   = fts4 + SZH;
    float* h2   = h1 + SZH;
    float* h3   = h2 + SZH;
    float* h4   = h3 + SZH;
    float* Zm   = h4 + SZH;                          // 16777216
    float* simf = Zm + SZH;                          // 18874368 (262144)
    float* rs   = simf + (size_t)N_H * N_H;          // 4096
    float* rinv = rs + N_NODES;
    float* cn2  = rinv + N_NODES;                    // 512
    float* cninv= cn2 + N_H;
    float* c1v  = cninv + N_H;
    float* c2v  = c1v + N_H;
    float* v1   = c2v + N_H;
    float* v2   = v1 + N_H;
    float* posn = v2 + N_H;                          // 4096
    float* simn = ws;                                // reuse fts+h region (64MB)

    init_out<<<1, 64, 0, stream>>>(out);

    dim3 g_fts(N_H / BN, N_NODES / BM);
    gemm_nt<0><<<g_fts, 256, 0, stream>>>(seq1, W1, nullptr, fts1, N_NODES, N_H, N_IN);
    gemm_nt<0><<<g_fts, 256, 0, stream>>>(seq1, W2, nullptr, fts2, N_NODES, N_H, N_IN);
    gemm_nt<0><<<g_fts, 256, 0, stream>>>(seq2, W1, nullptr, fts3, N_NODES, N_H, N_IN);
    gemm_nt<0><<<g_fts, 256, 0, stream>>>(seq2, W2, nullptr, fts4, N_NODES, N_H, N_IN);

    dim3 g_h(N_H / BN, N_NODES / BM);
    gemm_nn_bias_prelu<<<g_h, 256, 0, stream>>>(adj,  fts1, b1, a1, h1, N_NODES, N_H, N_NODES);
    gemm_nn_bias_prelu<<<g_h, 256, 0, stream>>>(diff, fts2, b2, a2, h2, N_NODES, N_H, N_NODES);
    gemm_nn_bias_prelu<<<g_h, 256, 0, stream>>>(adj,  fts3, b1, a1, h3, N_NODES, N_H, N_NODES);
    gemm_nn_bias_prelu<<<g_h, 256, 0, stream>>>(diff, fts4, b2, a2, h4, N_NODES, N_H, N_NODES);

    colmean_sigmoid<<<8, 256, 0, stream>>>(h1, c1v);
    colmean_sigmoid<<<8, 256, 0, stream>>>(h2, c2v);

    z_rowsumsq<<<(N_NODES * 64) / 256, 256, 0, stream>>>(h1, h2, Zm, rs);
    colsumsq_kernel<<<8, 256, 0, stream>>>(Zm, cn2);
    invnorm<<<16, 256, 0, stream>>>(rs, rinv, N_NODES);
    invnorm<<<2, 256, 0, stream>>>(cn2, cninv, N_H);

    bilinear_vec<<<(2 * N_H * 64) / 256, 256, 0, stream>>>(Wd, c1v, c2v, v1, v2);
    disc_kernel<<<(4 * N_NODES * 64) / 256, 256, 0, stream>>>(h1, h2, h3, h4, v1, v2, bd, out);

    gemm_tn_simf<<<dim3(N_H / BN, N_H / BM), 256, 0, stream>>>(Zm, cninv, simf);
    feat_sort_kernel<<<N_H, 256, 0, stream>>>(simf, fidx, out);

    // node similarity overwrites fts/h region (dead after disc)
    gemm_nt<1><<<dim3(N_NODES / BN, N_NODES / BM), 256, 0, stream>>>(
        Zm, Zm, rinv, simn, N_NODES, N_NODES, N_H);
    posn_kernel<<<N_NODES, 256, 0, stream>>>(simn, label, posn);
    node_sort_kernel<<<N_NODES, 256, 0, stream>>>(simn, nidx, posn, out);
}

// Round 3
// 967.093 us; speedup vs baseline: 3.2826x; 3.2826x over previous
//
#include <hip/hip_runtime.h>
#include <math.h>

#define N_NODES 4096
#define N_H     512
#define S_SEL   10

typedef __attribute__((ext_vector_type(4))) float  f32x4;
typedef __attribute__((ext_vector_type(8))) short  bf16x8;
typedef __attribute__((ext_vector_type(8))) unsigned short u16x8;

__device__ __forceinline__ unsigned short f2bf(float f) {
    union { float f; unsigned u; } v; v.f = f;
    unsigned r = v.u + 0x7FFFu + ((v.u >> 16) & 1u);
    return (unsigned short)(r >> 16);
}
__device__ __forceinline__ float bf2f(unsigned short u) {
    union { unsigned u; float f; } v; v.u = ((unsigned)u) << 16;
    return v.f;
}

// ---------------------------------------------------------------------------
// C = A[M,K] @ B[N,K]^T  via mfma_f32_16x16x32_bf16. 128x128 tile, 4 waves.
// A: f32 (AF32=1, converted in staging) or bf16. B: bf16.
// EPI 0: store bf16            (fts)
// EPI 1: f32, +bias[col&511], PReLU(slope)            (h13/h24)
// EPI 2: f32, exp(2*(x*scale[m]*scale[n])^2)          (sim_f)
// EPI 3: bf16, same epilogue                          (sim_n)
template <int EPI, int AF32>
__global__ __launch_bounds__(256) void mfma_nt(
    const void* __restrict__ Ap, const unsigned short* __restrict__ Bp,
    float* __restrict__ Cf, unsigned short* __restrict__ Cb,
    const float* __restrict__ bias, const float* __restrict__ slope,
    const float* __restrict__ scale, int M, int N, int K, int ldc)
{
    __shared__ unsigned short As[128 * 32];
    __shared__ unsigned short Bs[128 * 32];
    const int tid  = threadIdx.x;
    const int bm   = blockIdx.y * 128, bn = blockIdx.x * 128;
    const int lane = tid & 63, wid = tid >> 6;
    const int wr   = wid >> 1, wc = wid & 1;       // 2x2 waves -> 64x64 each
    const int sr   = tid >> 1, sc = (tid & 1) * 16; // staging: row, col-group

    f32x4 acc[4][4] = {};

    for (int k0 = 0; k0 < K; k0 += 32) {
        if (AF32) {
            const float* A = (const float*)Ap + (size_t)(bm + sr) * K + k0 + sc;
            f32x4 f0 = *(const f32x4*)A;
            f32x4 f1 = *(const f32x4*)(A + 4);
            f32x4 f2 = *(const f32x4*)(A + 8);
            f32x4 f3 = *(const f32x4*)(A + 12);
            u16x8 u0, u1;
            u0[0]=f2bf(f0[0]); u0[1]=f2bf(f0[1]); u0[2]=f2bf(f0[2]); u0[3]=f2bf(f0[3]);
            u0[4]=f2bf(f1[0]); u0[5]=f2bf(f1[1]); u0[6]=f2bf(f1[2]); u0[7]=f2bf(f1[3]);
            u1[0]=f2bf(f2[0]); u1[1]=f2bf(f2[1]); u1[2]=f2bf(f2[2]); u1[3]=f2bf(f2[3]);
            u1[4]=f2bf(f3[0]); u1[5]=f2bf(f3[1]); u1[6]=f2bf(f3[2]); u1[7]=f2bf(f3[3]);
            *(u16x8*)&As[sr * 32 + sc]     = u0;
            *(u16x8*)&As[sr * 32 + sc + 8] = u1;
        } else {
            const unsigned short* A = (const unsigned short*)Ap + (size_t)(bm + sr) * K + k0 + sc;
            *(u16x8*)&As[sr * 32 + sc]     = *(const u16x8*)A;
            *(u16x8*)&As[sr * 32 + sc + 8] = *(const u16x8*)(A + 8);
        }
        {
            const unsigned short* B = Bp + (size_t)(bn + sr) * K + k0 + sc;
            *(u16x8*)&Bs[sr * 32 + sc]     = *(const u16x8*)B;
            *(u16x8*)&Bs[sr * 32 + sc + 8] = *(const u16x8*)(B + 8);
        }
        __syncthreads();
        const int kg = (lane >> 4) * 8;
        const int ar = wr * 64 + (lane & 15);
        const int br = wc * 64 + (lane & 15);
        bf16x8 av[4], bv[4];
#pragma unroll
        for (int mi = 0; mi < 4; ++mi)
            av[mi] = *(const bf16x8*)&As[(ar + mi * 16) * 32 + kg];
#pragma unroll
        for (int ni = 0; ni < 4; ++ni)
            bv[ni] = *(const bf16x8*)&Bs[(br + ni * 16) * 32 + kg];
#pragma unroll
        for (int mi = 0; mi < 4; ++mi)
#pragma unroll
            for (int ni = 0; ni < 4; ++ni)
                acc[mi][ni] = __builtin_amdgcn_mfma_f32_16x16x32_bf16(
                    av[mi], bv[ni], acc[mi][ni], 0, 0, 0);
        __syncthreads();
    }

    // D layout: col = lane&15, row = (lane>>4)*4 + i   [m89-verified]
    const int r0 = bm + wr * 64 + ((lane >> 4) << 2);
    const int c0 = bn + wc * 64 + (lane & 15);
    const float sl = (EPI == 1) ? slope[0] : 0.f;
#pragma unroll
    for (int mi = 0; mi < 4; ++mi)
#pragma unroll
        for (int ni = 0; ni < 4; ++ni) {
            const int col = c0 + ni * 16;
#pragma unroll
            for (int i = 0; i < 4; ++i) {
                const int row = r0 + mi * 16 + i;
                float x = acc[mi][ni][i];
                if (EPI == 0) {
                    Cb[(size_t)row * ldc + col] = f2bf(x);
                } else if (EPI == 1) {
                    x += bias[col & (N_H - 1)];
                    x = x >= 0.f ? x : x * sl;
                    Cf[(size_t)row * ldc + col] = x;
                } else {
                    float v = x * scale[row] * scale[col];
                    float e = expf(2.f * v * v);
                    if (EPI == 2) Cf[(size_t)row * ldc + col] = e;
                    else          Cb[(size_t)row * ldc + col] = f2bf(e);
                }
            }
        }
}

// ---------------------------------------------------------------------------
__global__ void init_out(float* out)
{
    if (threadIdx.x == 0) { out[16384] = 0.f; out[16385] = 0.f; }
}

__global__ __launch_bounds__(256) void cast_bf16(
    const float* __restrict__ in, unsigned short* __restrict__ o, int n)
{
    int i = (blockIdx.x * 256 + threadIdx.x) * 4;
    if (i < n) {
        f32x4 f = *(const f32x4*)(in + i);
        o[i]     = f2bf(f[0]); o[i + 1] = f2bf(f[1]);
        o[i + 2] = f2bf(f[2]); o[i + 3] = f2bf(f[3]);
    }
}

// column mean (cols 0..511 of a [4096][1024] f32) -> sigmoid
__global__ __launch_bounds__(256) void colmean_sigmoid(
    const float* __restrict__ Hm, float* __restrict__ c)
{
    __shared__ float part[4][64];
    const int tcol = threadIdx.x & 63, trow = threadIdx.x >> 6;
    const int col = blockIdx.x * 64 + tcol;
    float s = 0.f;
    for (int r = trow * 1024; r < (trow + 1) * 1024; ++r)
        s += Hm[(size_t)r * 1024 + col];
    part[trow][tcol] = s;
    __syncthreads();
    if (trow == 0) {
        float t = part[0][tcol] + part[1][tcol] + part[2][tcol] + part[3][tcol];
        t *= (1.f / N_NODES);
        c[col] = 1.f / (1.f + expf(-t));
    }
}

// Z = h13[:, :512] + h24[:, :512] -> bf16 Zm; rinv = 1/max(||row||,1e-12)
__global__ __launch_bounds__(256) void z_kernel(
    const float* __restrict__ h13, const float* __restrict__ h24,
    unsigned short* __restrict__ Zm, float* __restrict__ rinv)
{
    const int w = (int)((blockIdx.x * 256u + threadIdx.x) >> 6);
    const int lane = threadIdx.x & 63;
    if (w >= N_NODES) return;
    float ss = 0.f;
#pragma unroll
    for (int t = 0; t < N_H; t += 64) {
        const size_t i4 = (size_t)w * 1024 + t + lane;
        float z = h13[i4] + h24[i4];
        Zm[(size_t)w * N_H + t + lane] = f2bf(z);
        ss = fmaf(z, z, ss);
    }
#pragma unroll
    for (int off = 32; off > 0; off >>= 1) ss += __shfl_down(ss, off, 64);
    if (lane == 0) rinv[w] = 1.f / fmaxf(sqrtf(ss), 1e-12f);
}

// 64x64 bf16 tile transpose: Zm[4096][512] -> Zt[512][4096]
__global__ __launch_bounds__(256) void transpose_bf(
    const unsigned short* __restrict__ in, unsigned short* __restrict__ outp)
{
    __shared__ unsigned short t[64][65];
    const int tid = threadIdx.x;
    const int r = tid >> 2, cq = (tid & 3) * 16;
    const int tr = blockIdx.y * 64, tc = blockIdx.x * 64;
    const unsigned short* src = in + (size_t)(tr + r) * N_H + tc + cq;
    u16x8 a = *(const u16x8*)src, b = *(const u16x8*)(src + 8);
#pragma unroll
    for (int q = 0; q < 8; ++q) { t[r][cq + q] = a[q]; t[r][cq + 8 + q] = b[q]; }
    __syncthreads();
    u16x8 o0, o1;
#pragma unroll
    for (int q = 0; q < 8; ++q) { o0[q] = t[cq + q][r]; o1[q] = t[cq + 8 + q][r]; }
    unsigned short* dst = outp + (size_t)(tc + r) * N_NODES + tr + cq;
    *(u16x8*)dst = o0; *(u16x8*)(dst + 8) = o1;
}

// cninv[i] = 1/max(||Zt row i||, 1e-12)  (512 rows of 4096 bf16)
__global__ __launch_bounds__(256) void cninv_kernel(
    const unsigned short* __restrict__ Zt, float* __restrict__ cninv)
{
    const int w = (int)((blockIdx.x * 256u + threadIdx.x) >> 6);
    const int lane = threadIdx.x & 63;
    if (w >= N_H) return;
    float ss = 0.f;
#pragma unroll
    for (int t = 0; t < N_NODES; t += 512) {
        u16x8 u = *(const u16x8*)(Zt + (size_t)w * N_NODES + t + lane * 8);
#pragma unroll
        for (int q = 0; q < 8; ++q) { float z = bf2f(u[q]); ss = fmaf(z, z, ss); }
    }
#pragma unroll
    for (int off = 32; off > 0; off >>= 1) ss += __shfl_down(ss, off, 64);
    if (lane == 0) cninv[w] = 1.f / fmaxf(sqrtf(ss), 1e-12f);
}

// v1 = Wd @ c1, v2 = Wd @ c2 (f32). one wave per output row.
__global__ __launch_bounds__(256) void bilinear_vec(
    const float* __restrict__ Wd, const float* __restrict__ c1,
    const float* __restrict__ c2, float* __restrict__ v1, float* __restrict__ v2)
{
    const int w = (int)((blockIdx.x * 256u + threadIdx.x) >> 6);
    const int lane = threadIdx.x & 63;
    if (w >= 2 * N_H) return;
    const float* c = (w < N_H) ? c1 : c2;
    float* v = (w < N_H) ? v1 : v2;
    const int r = (w < N_H) ? w : w - N_H;
    float s = 0.f;
#pragma unroll
    for (int t = 0; t < N_H; t += 64)
        s = fmaf(Wd[(size_t)r * N_H + t + lane], c[t + lane], s);
#pragma unroll
    for (int off = 32; off > 0; off >>= 1) s += __shfl_down(s, off, 64);
    if (lane == 0) v[r] = s;
}

// ret: [disc(h2,c1), disc(h1,c2), disc(h4,c1), disc(h3,c2)]
// h1=h13[:,0:512] h3=h13[:,512:1024] h2=h24[:,0:512] h4=h24[:,512:1024]
__global__ __launch_bounds__(256) void disc_kernel(
    const float* __restrict__ h13, const float* __restrict__ h24,
    const float* __restrict__ v1, const float* __restrict__ v2,
    const float* __restrict__ bd, float* __restrict__ out)
{
    const int w = (int)((blockIdx.x * 256u + threadIdx.x) >> 6);
    const int lane = threadIdx.x & 63;
    if (w >= 4 * N_NODES) return;
    const int seg = w >> 12, r = w & 4095;
    const float* hs = (seg == 0 || seg == 2) ? h24 : h13;
    const int coff = (seg >= 2) ? 512 : 0;
    const float* vs = (seg == 0 || seg == 2) ? v1 : v2;
    float s = 0.f;
#pragma unroll
    for (int t = 0; t < N_H; t += 64)
        s = fmaf(hs[(size_t)r * 1024 + coff + t + lane], vs[t + lane], s);
#pragma unroll
    for (int off = 32; off > 0; off >>= 1) s += __shfl_down(s, off, 64);
    if (lane == 0) out[(size_t)seg * N_NODES + r] = s + bd[0];
}

// ---------------------------------------------------------------------------
template <int L>
__device__ void bitonic_sort(float* buf)
{
    const int tid = threadIdx.x;
    for (int k = 2; k <= L; k <<= 1)
        for (int j = k >> 1; j > 0; j >>= 1) {
            for (int i = tid; i < L; i += 256) {
                int ixj = i ^ j;
                if (ixj > i) {
                    float a = buf[i], b = buf[ixj];
                    bool up = ((i & k) == 0);
                    if ((a > b) == up) { buf[i] = b; buf[ixj] = a; }
                }
            }
            __syncthreads();
        }
}

__global__ __launch_bounds__(256) void feat_sort_kernel(
    const float* __restrict__ simf, const int* __restrict__ fidx,
    float* __restrict__ out)
{
    __shared__ float buf[N_H];
    const int j = blockIdx.x, tid = threadIdx.x;
    for (int i = tid; i < N_H; i += 256) buf[i] = simf[(size_t)j * N_H + i];
    __syncthreads();
    bitonic_sort<N_H>(buf);
    if (tid == 0) {
        float neg = 0.f;
        for (int s = 0; s < S_SEL; ++s) neg += buf[fidx[s]];
        float pos = simf[(size_t)j * N_H + j];
        atomicAdd(out + 16384, (logf(neg) - logf(pos)) * (1.f / N_H));
    }
}

// ---------------------------------------------------------------------------
// Per column j (symmetric -> row j): pos = sim.row_j . label_row_j, and the
// 10 order statistics via 2-level (8-bit) radix select on bf16 keys.
__global__ __launch_bounds__(256) void node_select_kernel(
    const unsigned short* __restrict__ simb, const float* __restrict__ label,
    const int* __restrict__ nidx, float* __restrict__ out)
{
    __shared__ unsigned short keys[N_NODES];
    __shared__ unsigned hist[256], cum[256];
    __shared__ unsigned rpref[S_SEL], rneed[S_SEL];
    __shared__ float posred[4];
    const int j = blockIdx.x, tid = threadIdx.x;

    float pos = 0.f;
    for (int i = tid; i < N_NODES; i += 256) {
        unsigned short k = simb[(size_t)j * N_NODES + i];
        keys[i] = k;
        pos = fmaf(bf2f(k), label[(size_t)j * N_NODES + i], pos);
    }
#pragma unroll
    for (int off = 32; off > 0; off >>= 1) pos += __shfl_down(pos, off, 64);
    if ((tid & 63) == 0) posred[tid >> 6] = pos;
    if (tid == 0) {
        int rk[S_SEL];
        for (int s = 0; s < S_SEL; ++s) rk[s] = nidx[s];
        for (int a = 1; a < S_SEL; ++a) {
            int v = rk[a]; int b = a - 1;
            while (b >= 0 && rk[b] > v) { rk[b + 1] = rk[b]; --b; }
            rk[b + 1] = v;
        }
        for (int s = 0; s < S_SEL; ++s) { rneed[s] = (unsigned)rk[s]; rpref[s] = 0u; }
    }
    __syncthreads();

    for (int level = 0; level < 2; ++level) {
        const int shift = 8 - 8 * level;
        const unsigned maskhi = level ? 0xFF00u : 0u;
        for (int s = 0; s < S_SEL; ++s) {
            const bool redo = (s == 0) || ((rpref[s] & maskhi) != (rpref[s - 1] & maskhi));
            if (redo) {
                hist[tid] = 0u;
                __syncthreads();
                const unsigned pref = rpref[s] & maskhi;
                for (int i = tid; i < N_NODES; i += 256) {
                    unsigned k = keys[i];
                    if ((k & maskhi) == pref)
                        atomicAdd(&hist[(k >> shift) & 255u], 1u);
                }
                __syncthreads();
                if (tid < 64) {
                    unsigned h0 = hist[tid*4], h1 = hist[tid*4+1], h2 = hist[tid*4+2], h3 = hist[tid*4+3];
                    unsigned s0 = h0, s1 = s0 + h1, s2 = s1 + h2, s3 = s2 + h3;
                    unsigned tot = s3;
#pragma unroll
                    for (int off = 1; off < 64; off <<= 1) {
                        unsigned v = __shfl_up(tot, off, 64);
                        if (tid >= off) tot += v;
                    }
                    unsigned excl = tot - s3;
                    cum[tid*4] = s0 + excl; cum[tid*4+1] = s1 + excl;
                    cum[tid*4+2] = s2 + excl; cum[tid*4+3] = s3 + excl;
                }
                __syncthreads();
            }
            const unsigned need = rneed[s];
            if (cum[tid] > need && (tid == 0 || cum[tid - 1] <= need)) {
                rpref[s] |= ((unsigned)tid) << shift;
                rneed[s] = need - (tid ? cum[tid - 1] : 0u);
            }
            __syncthreads();
        }
    }
    if (tid == 0) {
        float neg = 0.f;
        for (int s = 0; s < S_SEL; ++s) neg += bf2f((unsigned short)rpref[s]);
        float posT = posred[0] + posred[1] + posred[2] + posred[3];
        atomicAdd(out + 16385, (logf(neg) - logf(posT)) * (1.f / N_NODES));
    }
}

// ---------------------------------------------------------------------------
extern "C" void kernel_launch(void* const* d_in, const int* in_sizes, int n_in,
                              void* d_out, int out_size, void* d_ws, size_t ws_size,
                              hipStream_t stream)
{
    const float* seq1  = (const float*)d_in[0];
    const float* seq2  = (const float*)d_in[1];
    const float* adj   = (const float*)d_in[2];
    const float* diff  = (const float*)d_in[3];
    const float* label = (const float*)d_in[4];
    const int*   fidx  = (const int*)d_in[5];
    const int*   nidx  = (const int*)d_in[6];
    const float* W1    = (const float*)d_in[7];
    const float* b1    = (const float*)d_in[8];
    const float* a1    = (const float*)d_in[9];
    const float* W2    = (const float*)d_in[10];
    const float* b2    = (const float*)d_in[11];
    const float* a2    = (const float*)d_in[12];
    const float* Wd    = (const float*)d_in[13];
    const float* bd    = (const float*)d_in[14];
    float* out = (float*)d_out;
    float* ws = (float*)d_ws;

    // ---- workspace layout (float slots; overlays are time-disjoint) ----
    unsigned short* simn_bf = (unsigned short*)(ws);             // 16.7M bf16 (late)
    float* h13   = ws + 8388608;                                 // [4096][1024] f32
    float* h24   = ws + 12582912;                                // [4096][1024] f32
    unsigned short* ftsT_A = (unsigned short*)(ws + 16777216);   // [1024][4096] bf16
    unsigned short* ftsT_B = (unsigned short*)(ws + 18874368);   // [1024][4096] bf16
    unsigned short* W1b    = (unsigned short*)(ws + 20971520);
    unsigned short* W2b    = (unsigned short*)(ws + 21102592);
    float* c1v   = ws + 21233664;
    float* c2v   = c1v + N_H;
    float* v1    = c2v + N_H;
    float* v2    = v1 + N_H;
    float* rinv  = v2 + N_H;               // 4096
    float* cninv = rinv + N_NODES;         // 512
    // overlays:
    unsigned short* s1b = (unsigned short*)h13;     // seq1 bf16 (dead before h13 written)
    unsigned short* s2b = (unsigned short*)h24;     // seq2 bf16
    unsigned short* Zm  = ftsT_A;                   // [4096][512] bf16 (ftsT dead)
    unsigned short* Zt  = ftsT_A + 2097152;         // [512][4096] bf16
    float* simf = (float*)ftsT_B;                   // [512][512] f32

    init_out<<<1, 64, 0, stream>>>(out);

    // casts
    cast_bf16<<<2048, 256, 0, stream>>>(seq1, s1b, 2097152);
    cast_bf16<<<2048, 256, 0, stream>>>(seq2, s2b, 2097152);
    cast_bf16<<<256, 256, 0, stream>>>(W1, W1b, 262144);
    cast_bf16<<<256, 256, 0, stream>>>(W2, W2b, 262144);

    // ftsT = W @ seq^T (NT): M=512, N=4096, K=512; rows [0,512)=seq1, [512,1024)=seq2
    dim3 gf(32, 4);
    mfma_nt<0,0><<<gf, 256, 0, stream>>>(W1b, s1b, nullptr, ftsT_A,                     nullptr, nullptr, nullptr, 512, 4096, 512, 4096);
    mfma_nt<0,0><<<gf, 256, 0, stream>>>(W1b, s2b, nullptr, ftsT_A + (size_t)512*4096,  nullptr, nullptr, nullptr, 512, 4096, 512, 4096);
    mfma_nt<0,0><<<gf, 256, 0, stream>>>(W2b, s1b, nullptr, ftsT_B,                     nullptr, nullptr, nullptr, 512, 4096, 512, 4096);
    mfma_nt<0,0><<<gf, 256, 0, stream>>>(W2b, s2b, nullptr, ftsT_B + (size_t)512*4096,  nullptr, nullptr, nullptr, 512, 4096, 512, 4096);

    // h13 = prelu(adj @ ftsT_A^T + b1), h24 = prelu(diff @ ftsT_B^T + b2)
    dim3 gh(8, 32);
    mfma_nt<1,1><<<gh, 256, 0, stream>>>(adj,  ftsT_A, h13, nullptr, b1, a1, nullptr, 4096, 1024, 4096, 1024);
    mfma_nt<1,1><<<gh, 256, 0, stream>>>(diff, ftsT_B, h24, nullptr, b2, a2, nullptr, 4096, 1024, 4096, 1024);

    colmean_sigmoid<<<8, 256, 0, stream>>>(h13, c1v);
    colmean_sigmoid<<<8, 256, 0, stream>>>(h24, c2v);

    z_kernel<<<1024, 256, 0, stream>>>(h13, h24, Zm, rinv);
    transpose_bf<<<dim3(8, 64), 256, 0, stream>>>(Zm, Zt);
    cninv_kernel<<<128, 256, 0, stream>>>(Zt, cninv);

    bilinear_vec<<<256, 256, 0, stream>>>(Wd, c1v, c2v, v1, v2);
    disc_kernel<<<4096, 256, 0, stream>>>(h13, h24, v1, v2, bd, out);

    // sim_f = exp(2*(Zt Zt^T * cninv_i * cninv_j)^2): M=N=512, K=4096
    mfma_nt<2,0><<<dim3(4, 4), 256, 0, stream>>>(Zt, Zt, simf, nullptr, nullptr, nullptr, cninv, 512, 512, 4096, 512);
    feat_sort_kernel<<<N_H, 256, 0, stream>>>(simf, fidx, out);

    // sim_n (bf16) = exp(2*(Z Z^T * rinv_i * rinv_j)^2): M=N=4096, K=512
    mfma_nt<3,0><<<dim3(32, 32), 256, 0, stream>>>(Zm, Zm, nullptr, simn_bf, nullptr, nullptr, rinv, 4096, 4096, 512, 4096);
    node_select_kernel<<<N_NODES, 256, 0, stream>>>(simn_bf, label, nidx, out);
}